// Round 1
// baseline (1583.681 us; speedup 1.0000x reference)
//
#include <hip/hip_runtime.h>
#include <hip/hip_bf16.h>

// ---------------------------------------------------------------------------
// TemporalAttention on MI355X (gfx950).
// b=4, n=8, h=32, w=32 (2*16 concat), c(tokens)=1024, d_emb=8192, H=8, Dk=Dv=256
// INPUTS: float32 (per reference). OUTPUT: float32. Internal: bf16 MFMA, f32 acc.
//
// All GEMMs use one fast path: bf16 A[M,K] x bf16 B[N,K] (weights pre-transposed
// to [N][K] bf16 once), 128x128 tile, BK=32, global_load_lds width-16 staging
// (m97 structure, ~870-910 TF class on big shapes).
//
// ws layout (peak 144 MiB + 32 B, time-phased):
//   [0,  64M)  x    bf16 [4096][8192]  residual; out-proj writes zo IN-PLACE here
//   [64, 80M)  q    bf16 [4096][2048]  -> z2 overwrites per-batch after PV
//   [80, 96M)  k    bf16 [4096][2048]
//   [96,112M)  vT   bf16 [4][8][256][1024]  (V stored transposed by proj epilogue)
//   [112,144M) wT scratch (32M): wT_q/k/v [2048][8192] -> per-batch sc f32
//              [8][1024][1024] (softmax rewrites rows in-place as bf16 P,
//              row stride 2048 ushorts) -> wT_o [8192][2048]
//   [144M,+32B) stats f32 [4][2]
// ---------------------------------------------------------------------------

typedef __attribute__((ext_vector_type(4))) float f32x4;
typedef __attribute__((ext_vector_type(8))) __bf16 bf16x8;
typedef __attribute__((ext_vector_type(8))) unsigned short ushort8;
typedef __attribute__((ext_vector_type(4))) unsigned short ushort4v;

static __device__ __forceinline__ float bf2f(unsigned short u) {
    unsigned int x = ((unsigned int)u) << 16;
    return __builtin_bit_cast(float, x);
}
static __device__ __forceinline__ unsigned short f2bf(float f) {
    unsigned int x = __builtin_bit_cast(unsigned int, f);
    unsigned int lsb = (x >> 16) & 1u;
    x += 0x7fffu + lsb;                 // round-to-nearest-even
    return (unsigned short)(x >> 16);
}

// async global->LDS, 16 B per lane. LDS dest must be wave-uniform base + lane*16;
// our per-lane lds ptr is exactly that pattern (chunk = wave*64 + lane).
static __device__ __forceinline__ void gload16(const unsigned short* g, unsigned short* l) {
    __builtin_amdgcn_global_load_lds(
        (const __attribute__((address_space(1))) void*)g,
        (__attribute__((address_space(3))) void*)l,
        16, 0, 0);
}

// ---------------------------------------------------------------------------
// Kernel 1: gather/concat + 'b n h w c -> b c (n h w)' transpose + 0.001*PE
// f32 in, bf16 out. (unchanged from verified version)
// ---------------------------------------------------------------------------
__global__ __launch_bounds__(256) void build_x_kernel(
    const float* __restrict__ ref_img,
    const float* __restrict__ hdmap,
    unsigned short* __restrict__ x)
{
    __shared__ float tile[32][72];
    int slab = blockIdx.y;                    // b*256 + n*32 + h
    int b = slab >> 8;
    int n = (slab >> 5) & 7;
    int h = slab & 31;
    int t0 = blockIdx.x * 64;
    int tid = threadIdx.x;

    {   // phase 1: coalesced read along t
        int w  = tid >> 3;      // 0..31
        int tg = tid & 7;       // 0..7 -> 8 f32 each
        const float* src = (w < 16)
            ? ref_img + ((size_t)(((b * 8 + n) * 32 + h) * 16 + w) * 1024 + t0 + tg * 8)
            : hdmap   + ((size_t)(((b * 8 + n) * 32 + h) * 16 + (w - 16)) * 1024 + t0 + tg * 8);
        *(f32x4*)&tile[w][tg * 8]     = *(const f32x4*)src;
        *(f32x4*)&tile[w][tg * 8 + 4] = *(const f32x4*)(src + 4);
    }
    __syncthreads();
    {   // phase 2: write x[t][f], f = n*1024 + h*32 + w; add 0.001*PE(t,f)
        int tau = tid >> 2;     // 0..63
        int wg  = tid & 3;      // 0..3
        int t = t0 + tau;
        const float L = 13.287712379549449f;  // log2(10000)
        ushort8 o;
        #pragma unroll
        for (int e = 0; e < 8; ++e) {
            int w = wg * 8 + e;
            int f = n * 1024 + h * 32 + w;
            int j = f >> 1;
            float ex = ((f & 1) ? (4.0f * (float)j + 2.0f) : (4.0f * (float)j)) * (1.0f / 8192.0f);
            float freq = exp2f(-ex * L);
            float arg = (float)t * freq;
            float pe = (f & 1) ? cosf(arg) : sinf(arg);
            o[e] = f2bf(tile[w][tau] + 0.001f * pe);
        }
        unsigned short* dst = x + ((size_t)(b * 1024 + t)) * 8192 + n * 1024 + h * 32 + wg * 8;
        *(ushort8*)dst = o;
    }
}

// ---------------------------------------------------------------------------
// Weight convert+transpose: f32 [K][N] row-major -> bf16 [N][K] row-major.
// 64x64 LDS tile; coalesced read along N, coalesced write along K.
// ---------------------------------------------------------------------------
__global__ __launch_bounds__(256) void wconv_kernel(
    const float* __restrict__ w, unsigned short* __restrict__ wt, int K, int N)
{
    __shared__ unsigned short tile[64][72];   // [k-local][n-local], padded
    int k0 = blockIdx.x * 64, n0 = blockIdx.y * 64;
    int tid = threadIdx.x;
    {
        int kl = tid >> 4;              // 0..15
        int nl = (tid & 15) * 4;        // 0..60
        #pragma unroll
        for (int i = 0; i < 4; ++i) {
            f32x4 v = *(const f32x4*)(w + (long)(k0 + kl + i * 16) * N + n0 + nl);
            tile[kl + i * 16][nl + 0] = f2bf(v[0]);
            tile[kl + i * 16][nl + 1] = f2bf(v[1]);
            tile[kl + i * 16][nl + 2] = f2bf(v[2]);
            tile[kl + i * 16][nl + 3] = f2bf(v[3]);
        }
    }
    __syncthreads();
    {
        int nl = tid >> 2;              // 0..63
        int kg = (tid & 3) * 16;        // 0,16,32,48
        ushort8 o0, o1;
        #pragma unroll
        for (int e = 0; e < 8; ++e) { o0[e] = tile[kg + e][nl]; o1[e] = tile[kg + 8 + e][nl]; }
        unsigned short* dst = wt + (long)(n0 + nl) * K + k0 + kg;
        *(ushort8*)dst = o0;
        *(ushort8*)(dst + 8) = o1;
    }
}

// ---------------------------------------------------------------------------
// MFMA GEMM, m97 structure: 128x128 tile, BK=32, 4 waves (64x64 each),
// linear LDS + global_load_lds dwordx4 staging, 16x16x32 bf16 MFMA.
// A bf16 [M,K] (lda), B bf16 [N,K] (ldb). z-batch via element strides sA2/sB2/sC2.
//   OUT_F32:    C is f32 (scores) else bf16
//   RESID:      add bf16 residual at C location (read-then-write in-place safe)
//   STORE_TRANS:write C transposed as vT[(row>>10)*2097152 + col*1024 + (row&1023)]
// M,N must be multiples of 128, K of 32 (all call sites satisfy this).
// ---------------------------------------------------------------------------
template<int OUT_F32, int RESID, int STORE_TRANS>
__global__ __launch_bounds__(256) void gemm_kernel(
    const unsigned short* __restrict__ A, const unsigned short* __restrict__ B,
    void* __restrict__ Cp, const unsigned short* __restrict__ resid,
    int K, int lda, int ldb, int ldc,
    long sA2, long sB2, long sC2, float alpha)
{
    __shared__ unsigned short As[128 * 32];
    __shared__ unsigned short Bs[128 * 32];

    int z = blockIdx.z;
    const unsigned short* Ab = A + (long)z * sA2;
    const unsigned short* Bb = B + (long)z * sB2;
    long coff = (long)z * sC2;

    int bm = blockIdx.y * 128, bn = blockIdx.x * 128;
    int tid = threadIdx.x;
    int lane = tid & 63;
    int wave = tid >> 6;
    int wm = (wave >> 1) * 64, wn = (wave & 1) * 64;
    int l15 = lane & 15, quad = lane >> 4;

    // staging chunks: chunk idx c -> LDS bytes [c*16, c*16+16) -> row c/4, k (c%4)*8
    int c1 = tid + 256;
    int r0 = tid >> 2, g0 = (tid & 3) * 8;
    int r1 = c1 >> 2,  g1 = (c1 & 3) * 8;

    const unsigned short* a0p = Ab + (long)(bm + r0) * lda + g0;
    const unsigned short* a1p = Ab + (long)(bm + r1) * lda + g1;
    const unsigned short* b0p = Bb + (long)(bn + r0) * ldb + g0;
    const unsigned short* b1p = Bb + (long)(bn + r1) * ldb + g1;
    unsigned short* al0 = As + tid * 8;
    unsigned short* al1 = As + c1 * 8;
    unsigned short* bl0 = Bs + tid * 8;
    unsigned short* bl1 = Bs + c1 * 8;

    f32x4 acc[4][4] = {};

    for (int k0 = 0; k0 < K; k0 += 32) {
        gload16(a0p + k0, al0);
        gload16(a1p + k0, al1);
        gload16(b0p + k0, bl0);
        gload16(b1p + k0, bl1);
        __syncthreads();                       // drains vmcnt before ds_read

        bf16x8 af[4], bfv[4];
        #pragma unroll
        for (int mi = 0; mi < 4; ++mi)
            af[mi] = *(const bf16x8*)&As[(wm + mi * 16 + l15) * 32 + quad * 8];
        #pragma unroll
        for (int ni = 0; ni < 4; ++ni)
            bfv[ni] = *(const bf16x8*)&Bs[(wn + ni * 16 + l15) * 32 + quad * 8];
        #pragma unroll
        for (int mi = 0; mi < 4; ++mi)
            #pragma unroll
            for (int ni = 0; ni < 4; ++ni)
                acc[mi][ni] = __builtin_amdgcn_mfma_f32_16x16x32_bf16(
                    af[mi], bfv[ni], acc[mi][ni], 0, 0, 0);
        __syncthreads();
    }

    // epilogue: C/D layout col=lane&15, row=quad*4+reg (verified mapping)
    if (STORE_TRANS) {
        unsigned short* vt = (unsigned short*)Cp;
        #pragma unroll
        for (int mi = 0; mi < 4; ++mi) {
            #pragma unroll
            for (int ni = 0; ni < 4; ++ni) {
                int row = bm + wm + mi * 16 + quad * 4;   // 4 consecutive rows
                int col = bn + wn + ni * 16 + l15;
                ushort4v o;
                #pragma unroll
                for (int r = 0; r < 4; ++r) o[r] = f2bf(acc[mi][ni][r] * alpha);
                *(ushort4v*)(vt + (long)(row >> 10) * 2097152
                                + (long)col * 1024 + (row & 1023)) = o;
            }
        }
    } else {
        #pragma unroll
        for (int mi = 0; mi < 4; ++mi)
            #pragma unroll
            for (int ni = 0; ni < 4; ++ni)
                #pragma unroll
                for (int r = 0; r < 4; ++r) {
                    int row = bm + wm + mi * 16 + quad * 4 + r;
                    int col = bn + wn + ni * 16 + l15;
                    float v = acc[mi][ni][r] * alpha;
                    long ci = coff + (long)row * ldc + col;
                    if (RESID) v += bf2f(resid[ci]);
                    if (OUT_F32) ((float*)Cp)[ci] = v;
                    else         ((unsigned short*)Cp)[ci] = f2bf(v);
                }
    }
}

// ---------------------------------------------------------------------------
// Row softmax over f32 scores; writes bf16 P IN-PLACE into the same buffer
// (row r bf16 at ushort offset r*2048 == first half of row r's f32 slot).
// Safe: every thread's row-chunk load precedes the block barriers that precede
// any write, and blocks own disjoint rows.
// ---------------------------------------------------------------------------
__global__ __launch_bounds__(256) void softmax_kernel(float* __restrict__ s)
{
    long row = blockIdx.x;                   // 8192 rows = 8 heads x 1024
    float* p = s + row * 1024;
    unsigned short* dst = (unsigned short*)s + row * 2048;
    int tid = threadIdx.x;
    int lane = tid & 63, wv = tid >> 6;

    f32x4 v = *(const f32x4*)(p + tid * 4);
    float m = fmaxf(fmaxf(v[0], v[1]), fmaxf(v[2], v[3]));
    #pragma unroll
    for (int off = 32; off; off >>= 1) m = fmaxf(m, __shfl_xor(m, off, 64));
    __shared__ float redm[4];
    if (lane == 0) redm[wv] = m;
    __syncthreads();
    m = fmaxf(fmaxf(redm[0], redm[1]), fmaxf(redm[2], redm[3]));

    f32x4 e;
    e[0] = __expf(v[0] - m); e[1] = __expf(v[1] - m);
    e[2] = __expf(v[2] - m); e[3] = __expf(v[3] - m);
    float sum = e[0] + e[1] + e[2] + e[3];
    #pragma unroll
    for (int off = 32; off; off >>= 1) sum += __shfl_xor(sum, off, 64);
    __shared__ float reds[4];
    if (lane == 0) reds[wv] = sum;
    __syncthreads();
    sum = reds[0] + reds[1] + reds[2] + reds[3];

    float inv = 1.0f / sum;
    ushort4v o;
    o[0] = f2bf(e[0] * inv); o[1] = f2bf(e[1] * inv);
    o[2] = f2bf(e[2] * inv); o[3] = f2bf(e[3] * inv);
    *(ushort4v*)(dst + tid * 4) = o;
}

// ---------------------------------------------------------------------------
// LayerNorm pass 1: per-batch sum/sumsq over bf16 zo [1024*8192].
// ---------------------------------------------------------------------------
__global__ __launch_bounds__(256) void ln_stats_kernel(
    const unsigned short* __restrict__ zo, float* __restrict__ stats)
{
    int b = blockIdx.y;
    const ushort8* p = (const ushort8*)(zo + (long)b * 8388608);
    float s = 0.f, sq = 0.f;
    for (int i = blockIdx.x * 256 + threadIdx.x; i < 1048576; i += 128 * 256) {
        ushort8 u = p[i];
        #pragma unroll
        for (int e = 0; e < 8; ++e) {
            float f = bf2f(u[e]);
            s += f; sq += f * f;
        }
    }
    #pragma unroll
    for (int off = 32; off; off >>= 1) {
        s += __shfl_xor(s, off, 64);
        sq += __shfl_xor(sq, off, 64);
    }
    __shared__ float rs[4], rq[4];
    int lane = threadIdx.x & 63, wv = threadIdx.x >> 6;
    if (lane == 0) { rs[wv] = s; rq[wv] = sq; }
    __syncthreads();
    if (threadIdx.x == 0) {
        atomicAdd(&stats[b * 2 + 0], rs[0] + rs[1] + rs[2] + rs[3]);
        atomicAdd(&stats[b * 2 + 1], rq[0] + rq[1] + rq[2] + rq[3]);
    }
}

// ---------------------------------------------------------------------------
// LayerNorm apply + gamma/beta (f32) + 'b (h w) (n c) -> b n c h w' permute.
// ---------------------------------------------------------------------------
__global__ __launch_bounds__(256) void ln_apply_kernel(
    const unsigned short* __restrict__ zo,
    const float* __restrict__ gamma,
    const float* __restrict__ beta,
    const float* __restrict__ stats,
    float* __restrict__ out)
{
    __shared__ float tile[64][65];
    int b = blockIdx.z, t0 = blockIdx.y * 64, f0 = blockIdx.x * 64;
    float mean = stats[b * 2 + 0] * (1.0f / 8388608.0f);
    float var  = stats[b * 2 + 1] * (1.0f / 8388608.0f) - mean * mean;
    float rstd = rsqrtf(var + 1e-6f);
    int tid = threadIdx.x;

    #pragma unroll
    for (int i = 0; i < 4; ++i) {
        int rt = (tid >> 4) + i * 16;   // token-local 0..63
        int c4 = (tid & 15) * 4;        // f-local
        long zi = (long)b * 8388608 + (long)(t0 + rt) * 8192 + f0 + c4;
        ushort4v zv = *(const ushort4v*)(zo + zi);
        long gi = (long)(t0 + rt) * 8192 + f0 + c4;
        f32x4 g  = *(const f32x4*)(gamma + gi);
        f32x4 bt = *(const f32x4*)(beta + gi);
        #pragma unroll
        for (int e = 0; e < 4; ++e)
            tile[rt][c4 + e] = (bf2f(zv[e]) - mean) * rstd * g[e] + bt[e];
    }
    __syncthreads();

    int fl = tid >> 2;                  // f-local 0..63
    int tg = tid & 3;                   // token group (16 tokens each)
    int f = f0 + fl;
    int np = f >> 10, cp = f & 1023;
    long obase = ((long)((b * 8 + np) * 1024 + cp)) * 1024 + t0 + tg * 16;
    #pragma unroll
    for (int c = 0; c < 4; ++c) {
        f32x4 o;
        #pragma unroll
        for (int e = 0; e < 4; ++e) o[e] = tile[tg * 16 + c * 4 + e][fl];
        *(f32x4*)(out + obase + c * 4) = o;
    }
}

// ---------------------------------------------------------------------------
extern "C" void kernel_launch(void* const* d_in, const int* in_sizes, int n_in,
                              void* d_out, int out_size, void* d_ws, size_t ws_size,
                              hipStream_t stream)
{
    const float* ref_img = (const float*)d_in[0];
    const float* hdmap   = (const float*)d_in[1];
    const float* w_q     = (const float*)d_in[2];
    const float* w_k     = (const float*)d_in[3];
    const float* w_v     = (const float*)d_in[4];
    const float* w_o     = (const float*)d_in[5];
    const float* gamma   = (const float*)d_in[6];
    const float* beta    = (const float*)d_in[7];

    char* ws = (char*)d_ws;
    const size_t MB = 1024 * 1024;
    unsigned short* x  = (unsigned short*)(ws);              // [0,64M) -> zo in-place
    unsigned short* q  = (unsigned short*)(ws + 64 * MB);    // [64,80M) -> z2
    unsigned short* k  = (unsigned short*)(ws + 80 * MB);    // [80,96M)
    unsigned short* vT = (unsigned short*)(ws + 96 * MB);    // [96,112M)
    unsigned short* wT = (unsigned short*)(ws + 112 * MB);   // [112,144M) scratch
    float* sc          = (float*)(ws + 112 * MB);            // same window as wT
    float* stats       = (float*)(ws + 144 * MB);            // 32 B
    unsigned short* z2 = q;
    unsigned short* zo = x;

    hipMemsetAsync(stats, 0, 32, stream);

    build_x_kernel<<<dim3(16, 1024), 256, 0, stream>>>(ref_img, hdmap, x);

    // --- QKV projections: convert each weight to bf16 [2048][8192], then GEMM ---
    wconv_kernel<<<dim3(128, 32), 256, 0, stream>>>(w_q, wT, 8192, 2048);
    gemm_kernel<0,0,0><<<dim3(16, 32, 1), 256, 0, stream>>>(
        x, wT, q, nullptr, 8192, 8192, 8192, 2048, 0, 0, 0, 1.0f);

    wconv_kernel<<<dim3(128, 32), 256, 0, stream>>>(w_k, wT, 8192, 2048);
    gemm_kernel<0,0,0><<<dim3(16, 32, 1), 256, 0, stream>>>(
        x, wT, k, nullptr, 8192, 8192, 8192, 2048, 0, 0, 0, 1.0f);

    wconv_kernel<<<dim3(128, 32), 256, 0, stream>>>(w_v, wT, 8192, 2048);
    gemm_kernel<0,0,1><<<dim3(16, 32, 1), 256, 0, stream>>>(    // V stored transposed
        x, wT, vT, nullptr, 8192, 8192, 8192, 0, 0, 0, 0, 1.0f);

    // --- attention, batch-sequential (sc window = 32 MiB, all 8 heads) ---
    for (int b = 0; b < 4; ++b) {
        long o2 = (long)b * 2097152;
        // sc[h] = (1/16) Q_bh @ K_bh^T   (both [1024][256] slices, B-trans natural)
        gemm_kernel<1,0,0><<<dim3(8, 8, 8), 256, 0, stream>>>(
            q + o2, k + o2, sc, nullptr,
            256, 2048, 2048, 1024, 256L, 256L, 1048576L, 0.0625f);
        softmax_kernel<<<8192, 256, 0, stream>>>(sc);            // writes bf16 P in-place
        // z2[b,h] = P_h @ V_bh : A = P bf16 (lda 2048, head stride 2097152 ushorts)
        gemm_kernel<0,0,0><<<dim3(2, 8, 8), 256, 0, stream>>>(
            (const unsigned short*)sc, vT + o2, z2 + o2, nullptr,
            1024, 2048, 1024, 2048, 2097152L, 262144L, 256L, 1.0f);
    }

    // --- out projection: wT_o bf16 [8192][2048]; zo written in-place over x ---
    wconv_kernel<<<dim3(32, 128), 256, 0, stream>>>(w_o, wT, 2048, 8192);
    gemm_kernel<0,1,0><<<dim3(64, 32, 1), 256, 0, stream>>>(
        z2, wT, zo, x, 2048, 2048, 2048, 8192, 0, 0, 0, 1.0f);

    ln_stats_kernel<<<dim3(128, 4), 256, 0, stream>>>(zo, stats);
    ln_apply_kernel<<<dim3(128, 16, 4), 256, 0, stream>>>(
        zo, gamma, beta, stats, (float*)d_out);
}

// Round 3
// 1495.498 us; speedup vs baseline: 1.0590x; 1.0590x over previous
//
#include <hip/hip_runtime.h>
#include <hip/hip_bf16.h>

// ---------------------------------------------------------------------------
// TemporalAttention on MI355X (gfx950).
// b=4, n=8, h=32, w=32 (2*16 concat), c(tokens)=1024, d_emb=8192, H=8, Dk=Dv=256
// INPUTS: float32 (per reference). OUTPUT: float32. Internal: bf16 MFMA, f32 acc.
//
// Big GEMMs (QKV, out-proj): 256x256 4-phase-per-K-tile schedule (T1+T2+T3/T4+T5)
// with counted vmcnt and wait-then-barrier publish discipline (vmcnt is per-wave;
// a barrier AFTER every wave's counted wait is what makes cooperative staging
// visible — reading after only one's own wait was round-2's NaN race).
// Small GEMMs (QK^T, PV): 128x128 m97-structure kernel.
//
// ws layout (peak 144 MiB + 32 B, time-phased):
//   [0,  64M)  x    bf16 [4096][8192]  residual; out-proj writes zo IN-PLACE here
//   [64, 80M)  q    bf16 [4096][2048]  -> z2 overwrites per-batch after PV
//   [80, 96M)  k    bf16 [4096][2048]
//   [96,112M)  vT   bf16 [4][8][256][1024]  (V stored transposed by proj epilogue)
//   [112,144M) wT scratch (32M): wT_q/k/v [2048][8192] -> per-batch sc f32
//              [8][1024][1024] (softmax rewrites rows in-place as bf16 P)
//              -> wT_o [8192][2048]
//   [144M,+32B) stats f32 [4][2]
// ---------------------------------------------------------------------------

typedef __attribute__((ext_vector_type(4))) float f32x4;
typedef __attribute__((ext_vector_type(8))) __bf16 bf16x8;
typedef __attribute__((ext_vector_type(8))) unsigned short ushort8;
typedef __attribute__((ext_vector_type(4))) unsigned short ushort4v;

static __device__ __forceinline__ float bf2f(unsigned short u) {
    unsigned int x = ((unsigned int)u) << 16;
    return __builtin_bit_cast(float, x);
}
static __device__ __forceinline__ unsigned short f2bf(float f) {
    unsigned int x = __builtin_bit_cast(unsigned int, f);
    unsigned int lsb = (x >> 16) & 1u;
    x += 0x7fffu + lsb;                 // round-to-nearest-even
    return (unsigned short)(x >> 16);
}

// async global->LDS, 16 B per lane. LDS dest must be wave-uniform base + lane*16.
static __device__ __forceinline__ void gload16(const unsigned short* g, unsigned short* l) {
    __builtin_amdgcn_global_load_lds(
        (const __attribute__((address_space(1))) void*)g,
        (__attribute__((address_space(3))) void*)l,
        16, 0, 0);
}

// ---------------------------------------------------------------------------
// Kernel 1: gather/concat + 'b n h w c -> b c (n h w)' transpose + 0.001*PE
// ---------------------------------------------------------------------------
__global__ __launch_bounds__(256) void build_x_kernel(
    const float* __restrict__ ref_img,
    const float* __restrict__ hdmap,
    unsigned short* __restrict__ x)
{
    __shared__ float tile[32][72];
    int slab = blockIdx.y;                    // b*256 + n*32 + h
    int b = slab >> 8;
    int n = (slab >> 5) & 7;
    int h = slab & 31;
    int t0 = blockIdx.x * 64;
    int tid = threadIdx.x;

    {   // phase 1: coalesced read along t
        int w  = tid >> 3;      // 0..31
        int tg = tid & 7;       // 0..7 -> 8 f32 each
        const float* src = (w < 16)
            ? ref_img + ((size_t)(((b * 8 + n) * 32 + h) * 16 + w) * 1024 + t0 + tg * 8)
            : hdmap   + ((size_t)(((b * 8 + n) * 32 + h) * 16 + (w - 16)) * 1024 + t0 + tg * 8);
        *(f32x4*)&tile[w][tg * 8]     = *(const f32x4*)src;
        *(f32x4*)&tile[w][tg * 8 + 4] = *(const f32x4*)(src + 4);
    }
    __syncthreads();
    {   // phase 2: write x[t][f], f = n*1024 + h*32 + w; add 0.001*PE(t,f)
        int tau = tid >> 2;     // 0..63
        int wg  = tid & 3;      // 0..3
        int t = t0 + tau;
        const float L = 13.287712379549449f;  // log2(10000)
        ushort8 o;
        #pragma unroll
        for (int e = 0; e < 8; ++e) {
            int w = wg * 8 + e;
            int f = n * 1024 + h * 32 + w;
            int j = f >> 1;
            float ex = ((f & 1) ? (4.0f * (float)j + 2.0f) : (4.0f * (float)j)) * (1.0f / 8192.0f);
            float freq = exp2f(-ex * L);
            float arg = (float)t * freq;
            float pe = (f & 1) ? cosf(arg) : sinf(arg);
            o[e] = f2bf(tile[w][tau] + 0.001f * pe);
        }
        unsigned short* dst = x + ((size_t)(b * 1024 + t)) * 8192 + n * 1024 + h * 32 + wg * 8;
        *(ushort8*)dst = o;
    }
}

// ---------------------------------------------------------------------------
// Weight convert+transpose: f32 [K][N] row-major -> bf16 [N][K] row-major.
// ---------------------------------------------------------------------------
__global__ __launch_bounds__(256) void wconv_kernel(
    const float* __restrict__ w, unsigned short* __restrict__ wt, int K, int N)
{
    __shared__ unsigned short tile[64][72];   // [k-local][n-local], padded
    int k0 = blockIdx.x * 64, n0 = blockIdx.y * 64;
    int tid = threadIdx.x;
    {
        int kl = tid >> 4;              // 0..15
        int nl = (tid & 15) * 4;        // 0..60
        #pragma unroll
        for (int i = 0; i < 4; ++i) {
            f32x4 v = *(const f32x4*)(w + (long)(k0 + kl + i * 16) * N + n0 + nl);
            tile[kl + i * 16][nl + 0] = f2bf(v[0]);
            tile[kl + i * 16][nl + 1] = f2bf(v[1]);
            tile[kl + i * 16][nl + 2] = f2bf(v[2]);
            tile[kl + i * 16][nl + 3] = f2bf(v[3]);
        }
    }
    __syncthreads();
    {
        int nl = tid >> 2;              // 0..63
        int kg = (tid & 3) * 16;        // 0,16,32,48
        ushort8 o0, o1;
        #pragma unroll
        for (int e = 0; e < 8; ++e) { o0[e] = tile[kg + e][nl]; o1[e] = tile[kg + 8 + e][nl]; }
        unsigned short* dst = wt + (long)(n0 + nl) * K + k0 + kg;
        *(ushort8*)dst = o0;
        *(ushort8*)(dst + 8) = o1;
    }
}

// ---------------------------------------------------------------------------
// gemm256: 256x256 tile, BK=64, 8 waves (2M x 4N), 4 phases per K-tile.
//   A bf16 [M,K] (lda), B bf16 [N,K] (ldb), C bf16 (ldc).
//   Half-tiles per K-tile: Ak0/Ak1/Bk0/Bk1, each 256 rows x 32 k = 16 KB.
//   LDS slot swizzle: phys = (logical + row>>1) & 3 (inverse on global source,
//   forward on ds_read addr) -> frag read is 2-way bank alias = free.
//   Pipeline: prefetch tile t+1 into buf[t+1 & 1] during t (never the read buf).
//   Publish discipline: s_waitcnt vmcnt(N) THEN s_barrier; ds_read only after
//   the barrier (vmcnt is per-wave; barrier makes all waves' loads visible).
//     prologue: 8 loads, vmcnt(4), barrier        -> Ak0/Bk0(0) published
//     end P2:   vmcnt(4) [last iter: vmcnt(0)]    -> Ak1/Bk1(t) published
//     end P4:   vmcnt(4) [skip last iter]         -> Ak0/Bk0(t+1) published
//   Counts are exact: 2 loads per half-tile, issue order Ak0,Bk0,Ak1,Bk1.
// Requires M%256==0, N%256==0, K%64==0, K>=128.
// ---------------------------------------------------------------------------
template<int RESID, int STORE_TRANS>
__global__ __launch_bounds__(512, 2) void gemm256_kernel(
    const unsigned short* __restrict__ A, const unsigned short* __restrict__ B,
    void* __restrict__ Cp, const unsigned short* __restrict__ resid,
    int K, int lda, int ldb, int ldc, float alpha)
{
    // [buf][half-tile: 0=Ak0 1=Ak1 2=Bk0 3=Bk1][8192 ushorts = 16KB]
    __shared__ unsigned short lds[2][4][8192];

    // bijective XCD swizzle (m204)
    int nwg = gridDim.x * gridDim.y;
    int flat = blockIdx.y * gridDim.x + blockIdx.x;
    int qq = nwg >> 3, rr = nwg & 7;
    int xcd = flat & 7, idx = flat >> 3;
    int sid = (xcd < rr ? xcd * (qq + 1) : rr * (qq + 1) + (xcd - rr) * qq) + idx;
    int bx = sid % gridDim.x, by = sid / gridDim.x;
    int bm = by * 256, bn = bx * 256;

    int tid = threadIdx.x;
    int lane = tid & 63, wave = tid >> 6;
    int l15 = lane & 15, quad = lane >> 4;
    int wm = (wave >> 2) * 128;     // 0 or 128
    int wn = (wave & 3) * 64;       // 0,64,128,192

    // per-thread frag LDS offsets (ushort units), identical for both k-halves
    int offA[8], offB[4];
    #pragma unroll
    for (int mi = 0; mi < 8; ++mi) {
        int r = wm + mi * 16 + l15;
        offA[mi] = r * 32 + (((quad + (r >> 1)) & 3) << 3);
    }
    #pragma unroll
    for (int ni = 0; ni < 4; ++ni) {
        int c = wn + ni * 16 + l15;
        offB[ni] = c * 32 + (((quad + (c >> 1)) & 3) << 3);
    }

    // staging: chunk c0=tid -> (row=tid>>2, phys slot tid&3); c1=tid+512 -> row+128.
    // logical slot = (phys - row>>1)&3 (inverse swizzle; row+128 preserves it).
    int row0 = tid >> 2;
    int ls   = ((tid & 3) - (row0 >> 1)) & 3;
    long a0 = (long)(bm + row0) * lda + ls * 8;
    long a1 = a0 + 128L * lda;
    long b0 = (long)(bn + row0) * ldb + ls * 8;
    long b1 = b0 + 128L * ldb;
    int d0 = tid * 8, d1 = tid * 8 + 4096;

    f32x4 acc[8][4] = {};
    int nt = K >> 6;

    // prologue: tile 0's four half-tiles, in checkpoint order, then publish Ak0/Bk0
    gload16(A + a0, &lds[0][0][d0]); gload16(A + a1, &lds[0][0][d1]);           // Ak0
    gload16(B + b0, &lds[0][2][d0]); gload16(B + b1, &lds[0][2][d1]);           // Bk0
    gload16(A + a0 + 32, &lds[0][1][d0]); gload16(A + a1 + 32, &lds[0][1][d1]); // Ak1
    gload16(B + b0 + 32, &lds[0][3][d0]); gload16(B + b1 + 32, &lds[0][3][d1]); // Bk1
    asm volatile("s_waitcnt vmcnt(4)" ::: "memory");
    __builtin_amdgcn_s_barrier();

    for (int t = 0; t < nt; ++t) {
        int cur = t & 1, nxt = cur ^ 1;
        long kn = (long)(t + 1) * 64;
        bool pf = (t + 1 < nt);
        bf16x8 af[4], bf[4];

        // ---- P1: ks=0, mi 0..3 (Ak0/Bk0(t) published by previous barrier) ----
        #pragma unroll
        for (int mi = 0; mi < 4; ++mi) af[mi] = *(const bf16x8*)&lds[cur][0][offA[mi]];
        #pragma unroll
        for (int ni = 0; ni < 4; ++ni) bf[ni] = *(const bf16x8*)&lds[cur][2][offB[ni]];
        if (pf) { gload16(A + a0 + kn, &lds[nxt][0][d0]);
                  gload16(A + a1 + kn, &lds[nxt][0][d1]); }
        __builtin_amdgcn_s_barrier();
        __builtin_amdgcn_s_setprio(1);
        #pragma unroll
        for (int mi = 0; mi < 4; ++mi)
            #pragma unroll
            for (int ni = 0; ni < 4; ++ni)
                acc[mi][ni] = __builtin_amdgcn_mfma_f32_16x16x32_bf16(
                    af[mi], bf[ni], acc[mi][ni], 0, 0, 0);
        __builtin_amdgcn_s_setprio(0);
        __builtin_amdgcn_s_barrier();

        // ---- P2: ks=0, mi 4..7 (B ks0 frags kept in regs) ----
        #pragma unroll
        for (int mi = 0; mi < 4; ++mi) af[mi] = *(const bf16x8*)&lds[cur][0][offA[mi + 4]];
        if (pf) { gload16(B + b0 + kn, &lds[nxt][2][d0]);
                  gload16(B + b1 + kn, &lds[nxt][2][d1]); }
        // publish Ak1/Bk1(t): wait (counted) then barrier; P3 reads after it
        if (pf) asm volatile("s_waitcnt vmcnt(4)" ::: "memory");
        else    asm volatile("s_waitcnt vmcnt(0)" ::: "memory");
        __builtin_amdgcn_s_barrier();
        __builtin_amdgcn_s_setprio(1);
        #pragma unroll
        for (int mi = 0; mi < 4; ++mi)
            #pragma unroll
            for (int ni = 0; ni < 4; ++ni)
                acc[mi + 4][ni] = __builtin_amdgcn_mfma_f32_16x16x32_bf16(
                    af[mi], bf[ni], acc[mi + 4][ni], 0, 0, 0);
        __builtin_amdgcn_s_setprio(0);
        __builtin_amdgcn_s_barrier();

        // ---- P3: ks=1, mi 0..3 ----
        #pragma unroll
        for (int mi = 0; mi < 4; ++mi) af[mi] = *(const bf16x8*)&lds[cur][1][offA[mi]];
        #pragma unroll
        for (int ni = 0; ni < 4; ++ni) bf[ni] = *(const bf16x8*)&lds[cur][3][offB[ni]];
        if (pf) { gload16(A + a0 + kn + 32, &lds[nxt][1][d0]);
                  gload16(A + a1 + kn + 32, &lds[nxt][1][d1]); }
        __builtin_amdgcn_s_barrier();
        __builtin_amdgcn_s_setprio(1);
        #pragma unroll
        for (int mi = 0; mi < 4; ++mi)
            #pragma unroll
            for (int ni = 0; ni < 4; ++ni)
                acc[mi][ni] = __builtin_amdgcn_mfma_f32_16x16x32_bf16(
                    af[mi], bf[ni], acc[mi][ni], 0, 0, 0);
        __builtin_amdgcn_s_setprio(0);
        __builtin_amdgcn_s_barrier();

        // ---- P4: ks=1, mi 4..7 ----
        #pragma unroll
        for (int mi = 0; mi < 4; ++mi) af[mi] = *(const bf16x8*)&lds[cur][1][offA[mi + 4]];
        if (pf) { gload16(B + b0 + kn + 32, &lds[nxt][3][d0]);
                  gload16(B + b1 + kn + 32, &lds[nxt][3][d1]); }
        // publish Ak0/Bk0(t+1) for next iteration's P1
        if (pf) asm volatile("s_waitcnt vmcnt(4)" ::: "memory");
        __builtin_amdgcn_s_barrier();
        __builtin_amdgcn_s_setprio(1);
        #pragma unroll
        for (int mi = 0; mi < 4; ++mi)
            #pragma unroll
            for (int ni = 0; ni < 4; ++ni)
                acc[mi + 4][ni] = __builtin_amdgcn_mfma_f32_16x16x32_bf16(
                    af[mi], bf[ni], acc[mi + 4][ni], 0, 0, 0);
        __builtin_amdgcn_s_setprio(0);
        __builtin_amdgcn_s_barrier();
    }

    // epilogue: C/D layout col=lane&15, row=quad*4+reg
    if (STORE_TRANS) {
        unsigned short* vt = (unsigned short*)Cp;
        #pragma unroll
        for (int mi = 0; mi < 8; ++mi) {
            #pragma unroll
            for (int ni = 0; ni < 4; ++ni) {
                int row = bm + wm + mi * 16 + quad * 4;   // 4 consecutive rows
                int col = bn + wn + ni * 16 + l15;
                ushort4v o;
                #pragma unroll
                for (int r = 0; r < 4; ++r) o[r] = f2bf(acc[mi][ni][r] * alpha);
                *(ushort4v*)(vt + (long)(row >> 10) * 2097152
                                + (long)col * 1024 + (row & 1023)) = o;
            }
        }
    } else {
        #pragma unroll
        for (int mi = 0; mi < 8; ++mi)
            #pragma unroll
            for (int ni = 0; ni < 4; ++ni)
                #pragma unroll
                for (int r = 0; r < 4; ++r) {
                    int row = bm + wm + mi * 16 + quad * 4 + r;
                    int col = bn + wn + ni * 16 + l15;
                    float v = acc[mi][ni][r] * alpha;
                    long ci = (long)row * ldc + col;
                    if (RESID) v += bf2f(resid[ci]);
                    ((unsigned short*)Cp)[ci] = f2bf(v);
                }
    }
}

// ---------------------------------------------------------------------------
// MFMA GEMM, m97 structure (used for attention QK^T and PV only).
// A bf16 [M,K] (lda), B bf16 [N,K] (ldb). z-batch via element strides.
// ---------------------------------------------------------------------------
template<int OUT_F32, int RESID, int STORE_TRANS>
__global__ __launch_bounds__(256) void gemm_kernel(
    const unsigned short* __restrict__ A, const unsigned short* __restrict__ B,
    void* __restrict__ Cp, const unsigned short* __restrict__ resid,
    int K, int lda, int ldb, int ldc,
    long sA2, long sB2, long sC2, float alpha)
{
    __shared__ unsigned short As[128 * 32];
    __shared__ unsigned short Bs[128 * 32];

    int z = blockIdx.z;
    const unsigned short* Ab = A + (long)z * sA2;
    const unsigned short* Bb = B + (long)z * sB2;
    long coff = (long)z * sC2;

    int bm = blockIdx.y * 128, bn = blockIdx.x * 128;
    int tid = threadIdx.x;
    int lane = tid & 63;
    int wave = tid >> 6;
    int wm = (wave >> 1) * 64, wn = (wave & 1) * 64;
    int l15 = lane & 15, quad = lane >> 4;

    int c1 = tid + 256;
    int r0 = tid >> 2, g0 = (tid & 3) * 8;
    int r1 = c1 >> 2,  g1 = (c1 & 3) * 8;

    const unsigned short* a0p = Ab + (long)(bm + r0) * lda + g0;
    const unsigned short* a1p = Ab + (long)(bm + r1) * lda + g1;
    const unsigned short* b0p = Bb + (long)(bn + r0) * ldb + g0;
    const unsigned short* b1p = Bb + (long)(bn + r1) * ldb + g1;
    unsigned short* al0 = As + tid * 8;
    unsigned short* al1 = As + c1 * 8;
    unsigned short* bl0 = Bs + tid * 8;
    unsigned short* bl1 = Bs + c1 * 8;

    f32x4 acc[4][4] = {};

    for (int k0 = 0; k0 < K; k0 += 32) {
        gload16(a0p + k0, al0);
        gload16(a1p + k0, al1);
        gload16(b0p + k0, bl0);
        gload16(b1p + k0, bl1);
        __syncthreads();

        bf16x8 af[4], bfv[4];
        #pragma unroll
        for (int mi = 0; mi < 4; ++mi)
            af[mi] = *(const bf16x8*)&As[(wm + mi * 16 + l15) * 32 + quad * 8];
        #pragma unroll
        for (int ni = 0; ni < 4; ++ni)
            bfv[ni] = *(const bf16x8*)&Bs[(wn + ni * 16 + l15) * 32 + quad * 8];
        #pragma unroll
        for (int mi = 0; mi < 4; ++mi)
            #pragma unroll
            for (int ni = 0; ni < 4; ++ni)
                acc[mi][ni] = __builtin_amdgcn_mfma_f32_16x16x32_bf16(
                    af[mi], bfv[ni], acc[mi][ni], 0, 0, 0);
        __syncthreads();
    }

    if (STORE_TRANS) {
        unsigned short* vt = (unsigned short*)Cp;
        #pragma unroll
        for (int mi = 0; mi < 4; ++mi) {
            #pragma unroll
            for (int ni = 0; ni < 4; ++ni) {
                int row = bm + wm + mi * 16 + quad * 4;
                int col = bn + wn + ni * 16 + l15;
                ushort4v o;
                #pragma unroll
                for (int r = 0; r < 4; ++r) o[r] = f2bf(acc[mi][ni][r] * alpha);
                *(ushort4v*)(vt + (long)(row >> 10) * 2097152
                                + (long)col * 1024 + (row & 1023)) = o;
            }
        }
    } else {
        #pragma unroll
        for (int mi = 0; mi < 4; ++mi)
            #pragma unroll
            for (int ni = 0; ni < 4; ++ni)
                #pragma unroll
                for (int r = 0; r < 4; ++r) {
                    int row = bm + wm + mi * 16 + quad * 4 + r;
                    int col = bn + wn + ni * 16 + l15;
                    float v = acc[mi][ni][r] * alpha;
                    long ci = coff + (long)row * ldc + col;
                    if (RESID) v += bf2f(resid[ci]);
                    if (OUT_F32) ((float*)Cp)[ci] = v;
                    else         ((unsigned short*)Cp)[ci] = f2bf(v);
                }
    }
}

// ---------------------------------------------------------------------------
// Row softmax over f32 scores; writes bf16 P IN-PLACE (row r bf16 at ushort
// offset r*2048). Safe: loads precede the block barriers that precede writes.
// ---------------------------------------------------------------------------
__global__ __launch_bounds__(256) void softmax_kernel(float* __restrict__ s)
{
    long row = blockIdx.x;                   // 8192 rows = 8 heads x 1024
    float* p = s + row * 1024;
    unsigned short* dst = (unsigned short*)s + row * 2048;
    int tid = threadIdx.x;
    int lane = tid & 63, wv = tid >> 6;

    f32x4 v = *(const f32x4*)(p + tid * 4);
    float m = fmaxf(fmaxf(v[0], v[1]), fmaxf(v[2], v[3]));
    #pragma unroll
    for (int off = 32; off; off >>= 1) m = fmaxf(m, __shfl_xor(m, off, 64));
    __shared__ float redm[4];
    if (lane == 0) redm[wv] = m;
    __syncthreads();
    m = fmaxf(fmaxf(redm[0], redm[1]), fmaxf(redm[2], redm[3]));

    f32x4 e;
    e[0] = __expf(v[0] - m); e[1] = __expf(v[1] - m);
    e[2] = __expf(v[2] - m); e[3] = __expf(v[3] - m);
    float sum = e[0] + e[1] + e[2] + e[3];
    #pragma unroll
    for (int off = 32; off; off >>= 1) sum += __shfl_xor(sum, off, 64);
    __shared__ float reds[4];
    if (lane == 0) reds[wv] = sum;
    __syncthreads();
    sum = reds[0] + reds[1] + reds[2] + reds[3];

    float inv = 1.0f / sum;
    ushort4v o;
    o[0] = f2bf(e[0] * inv); o[1] = f2bf(e[1] * inv);
    o[2] = f2bf(e[2] * inv); o[3] = f2bf(e[3] * inv);
    *(ushort4v*)(dst + tid * 4) = o;
}

// ---------------------------------------------------------------------------
// LayerNorm pass 1: per-batch sum/sumsq over bf16 zo [1024*8192].
// ---------------------------------------------------------------------------
__global__ __launch_bounds__(256) void ln_stats_kernel(
    const unsigned short* __restrict__ zo, float* __restrict__ stats)
{
    int b = blockIdx.y;
    const ushort8* p = (const ushort8*)(zo + (long)b * 8388608);
    float s = 0.f, sq = 0.f;
    for (int i = blockIdx.x * 256 + threadIdx.x; i < 1048576; i += 128 * 256) {
        ushort8 u = p[i];
        #pragma unroll
        for (int e = 0; e < 8; ++e) {
            float f = bf2f(u[e]);
            s += f; sq += f * f;
        }
    }
    #pragma unroll
    for (int off = 32; off; off >>= 1) {
        s += __shfl_xor(s, off, 64);
        sq += __shfl_xor(sq, off, 64);
    }
    __shared__ float rs[4], rq[4];
    int lane = threadIdx.x & 63, wv = threadIdx.x >> 6;
    if (lane == 0) { rs[wv] = s; rq[wv] = sq; }
    __syncthreads();
    if (threadIdx.x == 0) {
        atomicAdd(&stats[b * 2 + 0], rs[0] + rs[1] + rs[2] + rs[3]);
        atomicAdd(&stats[b * 2 + 1], rq[0] + rq[1] + rq[2] + rq[3]);
    }
}

// ---------------------------------------------------------------------------
// LayerNorm apply + gamma/beta (f32) + 'b (h w) (n c) -> b n c h w' permute.
// ---------------------------------------------------------------------------
__global__ __launch_bounds__(256) void ln_apply_kernel(
    const unsigned short* __restrict__ zo,
    const float* __restrict__ gamma,
    const float* __restrict__ beta,
    const float* __restrict__ stats,
    float* __restrict__ out)
{
    __shared__ float tile[64][65];
    int b = blockIdx.z, t0 = blockIdx.y * 64, f0 = blockIdx.x * 64;
    float mean = stats[b * 2 + 0] * (1.0f / 8388608.0f);
    float var  = stats[b * 2 + 1] * (1.0f / 8388608.0f) - mean * mean;
    float rstd = rsqrtf(var + 1e-6f);
    int tid = threadIdx.x;

    #pragma unroll
    for (int i = 0; i < 4; ++i) {
        int rt = (tid >> 4) + i * 16;   // token-local 0..63
        int c4 = (tid & 15) * 4;        // f-local
        long zi = (long)b * 8388608 + (long)(t0 + rt) * 8192 + f0 + c4;
        ushort4v zv = *(const ushort4v*)(zo + zi);
        long gi = (long)(t0 + rt) * 8192 + f0 + c4;
        f32x4 g  = *(const f32x4*)(gamma + gi);
        f32x4 bt = *(const f32x4*)(beta + gi);
        #pragma unroll
        for (int e = 0; e < 4; ++e)
            tile[rt][c4 + e] = (bf2f(zv[e]) - mean) * rstd * g[e] + bt[e];
    }
    __syncthreads();

    int fl = tid >> 2;                  // f-local 0..63
    int tg = tid & 3;                   // token group (16 tokens each)
    int f = f0 + fl;
    int np = f >> 10, cp = f & 1023;
    long obase = ((long)((b * 8 + np) * 1024 + cp)) * 1024 + t0 + tg * 16;
    #pragma unroll
    for (int c = 0; c < 4; ++c) {
        f32x4 o;
        #pragma unroll
        for (int e = 0; e < 4; ++e) o[e] = tile[tg * 16 + c * 4 + e][fl];
        *(f32x4*)(out + obase + c * 4) = o;
    }
}

// ---------------------------------------------------------------------------
extern "C" void kernel_launch(void* const* d_in, const int* in_sizes, int n_in,
                              void* d_out, int out_size, void* d_ws, size_t ws_size,
                              hipStream_t stream)
{
    const float* ref_img = (const float*)d_in[0];
    const float* hdmap   = (const float*)d_in[1];
    const float* w_q     = (const float*)d_in[2];
    const float* w_k     = (const float*)d_in[3];
    const float* w_v     = (const float*)d_in[4];
    const float* w_o     = (const float*)d_in[5];
    const float* gamma   = (const float*)d_in[6];
    const float* beta    = (const float*)d_in[7];

    char* ws = (char*)d_ws;
    const size_t MB = 1024 * 1024;
    unsigned short* x  = (unsigned short*)(ws);              // [0,64M) -> zo in-place
    unsigned short* q  = (unsigned short*)(ws + 64 * MB);    // [64,80M) -> z2
    unsigned short* k  = (unsigned short*)(ws + 80 * MB);    // [80,96M)
    unsigned short* vT = (unsigned short*)(ws + 96 * MB);    // [96,112M)
    unsigned short* wT = (unsigned short*)(ws + 112 * MB);   // [112,144M) scratch
    float* sc          = (float*)(ws + 112 * MB);            // same window as wT
    float* stats       = (float*)(ws + 144 * MB);            // 32 B
    unsigned short* z2 = q;
    unsigned short* zo = x;

    hipMemsetAsync(stats, 0, 32, stream);

    build_x_kernel<<<dim3(16, 1024), 256, 0, stream>>>(ref_img, hdmap, x);

    // --- QKV projections: convert each weight to bf16 [2048][8192], then GEMM ---
    wconv_kernel<<<dim3(128, 32), 256, 0, stream>>>(w_q, wT, 8192, 2048);
    gemm256_kernel<0,0><<<dim3(8, 16), 512, 0, stream>>>(
        x, wT, q, nullptr, 8192, 8192, 8192, 2048, 1.0f);

    wconv_kernel<<<dim3(128, 32), 256, 0, stream>>>(w_k, wT, 8192, 2048);
    gemm256_kernel<0,0><<<dim3(8, 16), 512, 0, stream>>>(
        x, wT, k, nullptr, 8192, 8192, 8192, 2048, 1.0f);

    wconv_kernel<<<dim3(128, 32), 256, 0, stream>>>(w_v, wT, 8192, 2048);
    gemm256_kernel<0,1><<<dim3(8, 16), 512, 0, stream>>>(    // V stored transposed
        x, wT, vT, nullptr, 8192, 8192, 8192, 0, 1.0f);

    // --- attention, batch-sequential (sc window = 32 MiB, all 8 heads) ---
    for (int b = 0; b < 4; ++b) {
        long o2 = (long)b * 2097152;
        // sc[h] = (1/16) Q_bh @ K_bh^T
        gemm_kernel<1,0,0><<<dim3(8, 8, 8), 256, 0, stream>>>(
            q + o2, k + o2, sc, nullptr,
            256, 2048, 2048, 1024, 256L, 256L, 1048576L, 0.0625f);
        softmax_kernel<<<8192, 256, 0, stream>>>(sc);        // writes bf16 P in-place
        // z2[b,h] = P_h @ V_bh
        gemm_kernel<0,0,0><<<dim3(2, 8, 8), 256, 0, stream>>>(
            (const unsigned short*)sc, vT + o2, z2 + o2, nullptr,
            1024, 2048, 1024, 2048, 2097152L, 262144L, 256L, 1.0f);
    }

    // --- out projection: wT_o bf16 [8192][2048]; zo written in-place over x ---
    wconv_kernel<<<dim3(32, 128), 256, 0, stream>>>(w_o, wT, 2048, 8192);
    gemm256_kernel<1,0><<<dim3(32, 16), 512, 0, stream>>>(
        z2, wT, zo, x, 2048, 2048, 2048, 8192, 1.0f);

    ln_stats_kernel<<<dim3(128, 4), 256, 0, stream>>>(zo, stats);
    ln_apply_kernel<<<dim3(128, 16, 4), 256, 0, stream>>>(
        zo, gamma, beta, stats, (float*)d_out);
}

// Round 4
// 1344.626 us; speedup vs baseline: 1.1778x; 1.1122x over previous
//
#include <hip/hip_runtime.h>
#include <hip/hip_bf16.h>

// ---------------------------------------------------------------------------
// TemporalAttention on MI355X (gfx950).
// b=4, n=8, h=32, w=32 (2*16 concat), c(tokens)=1024, d_emb=8192, H=8, Dk=Dv=256
// INPUTS: float32 (per reference). OUTPUT: float32. Internal: bf16 MFMA, f32 acc.
//
// Big GEMMs:
//   QKV (M4096 N2048 K8192): gemm256x128 — BM=256 BN=128 4-phase pipeline,
//     grid 16x16 = 256 wgs = full chip (round-3 lesson: 256x256 gave 128 wgs
//     = half chip idle, occupancy 10.7%).
//   out-proj (M4096 N8192): gemm256 — BM=BN=256, 512 wgs = 2 full rounds.
// Both use counted-vmcnt wait-then-barrier publish (vmcnt is per-wave; the
// barrier after every wave's counted wait publishes cooperative staging).
// Small GEMMs (QK^T, PV): 128x128 m97-structure kernel.
//
// ws layout (peak 144 MiB + 32 B, time-phased):
//   [0,  64M)  x    bf16 [4096][8192]  residual; out-proj writes zo IN-PLACE here
//   [64, 80M)  q    bf16 [4096][2048]  -> z2 overwrites per-batch after PV
//   [80, 96M)  k    bf16 [4096][2048]
//   [96,112M)  vT   bf16 [4][8][256][1024]  (V stored transposed by proj epilogue)
//   [112,144M) wT scratch (32M): wT_q/k/v [2048][8192] -> per-batch sc f32
//              [8][1024][1024] (softmax rewrites rows in-place as bf16 P)
//              -> wT_o [8192][2048]
//   [144M,+32B) stats f32 [4][2]
// ---------------------------------------------------------------------------

typedef __attribute__((ext_vector_type(4))) float f32x4;
typedef __attribute__((ext_vector_type(8))) __bf16 bf16x8;
typedef __attribute__((ext_vector_type(8))) unsigned short ushort8;
typedef __attribute__((ext_vector_type(4))) unsigned short ushort4v;

static __device__ __forceinline__ float bf2f(unsigned short u) {
    unsigned int x = ((unsigned int)u) << 16;
    return __builtin_bit_cast(float, x);
}
static __device__ __forceinline__ unsigned short f2bf(float f) {
    unsigned int x = __builtin_bit_cast(unsigned int, f);
    unsigned int lsb = (x >> 16) & 1u;
    x += 0x7fffu + lsb;                 // round-to-nearest-even
    return (unsigned short)(x >> 16);
}

// async global->LDS, 16 B per lane. LDS dest must be wave-uniform base + lane*16.
static __device__ __forceinline__ void gload16(const unsigned short* g, unsigned short* l) {
    __builtin_amdgcn_global_load_lds(
        (const __attribute__((address_space(1))) void*)g,
        (__attribute__((address_space(3))) void*)l,
        16, 0, 0);
}

// ---------------------------------------------------------------------------
// Kernel 1: gather/concat + 'b n h w c -> b c (n h w)' transpose + 0.001*PE
// ---------------------------------------------------------------------------
__global__ __launch_bounds__(256) void build_x_kernel(
    const float* __restrict__ ref_img,
    const float* __restrict__ hdmap,
    unsigned short* __restrict__ x)
{
    __shared__ float tile[32][72];
    int slab = blockIdx.y;                    // b*256 + n*32 + h
    int b = slab >> 8;
    int n = (slab >> 5) & 7;
    int h = slab & 31;
    int t0 = blockIdx.x * 64;
    int tid = threadIdx.x;

    {   // phase 1: coalesced read along t
        int w  = tid >> 3;      // 0..31
        int tg = tid & 7;       // 0..7 -> 8 f32 each
        const float* src = (w < 16)
            ? ref_img + ((size_t)(((b * 8 + n) * 32 + h) * 16 + w) * 1024 + t0 + tg * 8)
            : hdmap   + ((size_t)(((b * 8 + n) * 32 + h) * 16 + (w - 16)) * 1024 + t0 + tg * 8);
        *(f32x4*)&tile[w][tg * 8]     = *(const f32x4*)src;
        *(f32x4*)&tile[w][tg * 8 + 4] = *(const f32x4*)(src + 4);
    }
    __syncthreads();
    {   // phase 2: write x[t][f], f = n*1024 + h*32 + w; add 0.001*PE(t,f)
        int tau = tid >> 2;     // 0..63
        int wg  = tid & 3;      // 0..3
        int t = t0 + tau;
        const float L = 13.287712379549449f;  // log2(10000)
        ushort8 o;
        #pragma unroll
        for (int e = 0; e < 8; ++e) {
            int w = wg * 8 + e;
            int f = n * 1024 + h * 32 + w;
            int j = f >> 1;
            float ex = ((f & 1) ? (4.0f * (float)j + 2.0f) : (4.0f * (float)j)) * (1.0f / 8192.0f);
            float freq = exp2f(-ex * L);
            float arg = (float)t * freq;
            float pe = (f & 1) ? cosf(arg) : sinf(arg);
            o[e] = f2bf(tile[w][tau] + 0.001f * pe);
        }
        unsigned short* dst = x + ((size_t)(b * 1024 + t)) * 8192 + n * 1024 + h * 32 + wg * 8;
        *(ushort8*)dst = o;
    }
}

// ---------------------------------------------------------------------------
// Weight convert+transpose: f32 [K][N] row-major -> bf16 [N][K] row-major.
// ---------------------------------------------------------------------------
__global__ __launch_bounds__(256) void wconv_kernel(
    const float* __restrict__ w, unsigned short* __restrict__ wt, int K, int N)
{
    __shared__ unsigned short tile[64][72];   // [k-local][n-local], padded
    int k0 = blockIdx.x * 64, n0 = blockIdx.y * 64;
    int tid = threadIdx.x;
    {
        int kl = tid >> 4;              // 0..15
        int nl = (tid & 15) * 4;        // 0..60
        #pragma unroll
        for (int i = 0; i < 4; ++i) {
            f32x4 v = *(const f32x4*)(w + (long)(k0 + kl + i * 16) * N + n0 + nl);
            tile[kl + i * 16][nl + 0] = f2bf(v[0]);
            tile[kl + i * 16][nl + 1] = f2bf(v[1]);
            tile[kl + i * 16][nl + 2] = f2bf(v[2]);
            tile[kl + i * 16][nl + 3] = f2bf(v[3]);
        }
    }
    __syncthreads();
    {
        int nl = tid >> 2;              // 0..63
        int kg = (tid & 3) * 16;        // 0,16,32,48
        ushort8 o0, o1;
        #pragma unroll
        for (int e = 0; e < 8; ++e) { o0[e] = tile[kg + e][nl]; o1[e] = tile[kg + 8 + e][nl]; }
        unsigned short* dst = wt + (long)(n0 + nl) * K + k0 + kg;
        *(ushort8*)dst = o0;
        *(ushort8*)(dst + 8) = o1;
    }
}

// ---------------------------------------------------------------------------
// gemm256x128: BM=256, BN=128, BK=64, 8 waves (4M x 2N, wave tile 64x64).
//   A bf16 [M,K] (lda), B bf16 [N,K] (ldb), C bf16 (ldc).
//   Half-tiles: Ak0/Ak1 = 256x32 (16KB), Bk0/Bk1 = 128x32 (8KB); 96KB total.
//   6 loads/thread/K-tile, issue order Ak0(2),Bk0(1),Ak1(2),Bk1(1).
//   Publish (wait-then-barrier): prologue vmcnt(3); end-P2 vmcnt(3)
//   [last iter vmcnt(0)]; end-P4 vmcnt(3) [skip last iter].
//   Slot swizzle as gemm256: phys = (logical + row>>1) & 3.
// Requires M%256==0, N%128==0, K%64==0, K>=128. Grid (N/128, M/256), 512 thr.
// ---------------------------------------------------------------------------
template<int STORE_TRANS>
__global__ __launch_bounds__(512, 2) void gemm256x128_kernel(
    const unsigned short* __restrict__ A, const unsigned short* __restrict__ B,
    void* __restrict__ Cp,
    int K, int lda, int ldb, int ldc, float alpha)
{
    __shared__ unsigned short ldsA[2][2][8192];   // [buf][khalf][256*32]
    __shared__ unsigned short ldsB[2][2][4096];   // [buf][khalf][128*32]

    // bijective XCD swizzle (m204)
    int nwg = gridDim.x * gridDim.y;
    int flat = blockIdx.y * gridDim.x + blockIdx.x;
    int qq = nwg >> 3, rr = nwg & 7;
    int xcd = flat & 7, idx = flat >> 3;
    int sid = (xcd < rr ? xcd * (qq + 1) : rr * (qq + 1) + (xcd - rr) * qq) + idx;
    int bx = sid % gridDim.x, by = sid / gridDim.x;
    int bm = by * 256, bn = bx * 128;

    int tid = threadIdx.x;
    int lane = tid & 63, wave = tid >> 6;
    int l15 = lane & 15, quad = lane >> 4;
    int wm = (wave >> 1) * 64;      // 0,64,128,192
    int wn = (wave & 1) * 64;       // 0,64

    int offA[4], offB[4];
    #pragma unroll
    for (int mi = 0; mi < 4; ++mi) {
        int r = wm + mi * 16 + l15;
        offA[mi] = r * 32 + (((quad + (r >> 1)) & 3) << 3);
    }
    #pragma unroll
    for (int ni = 0; ni < 4; ++ni) {
        int c = wn + ni * 16 + l15;
        offB[ni] = c * 32 + (((quad + (c >> 1)) & 3) << 3);
    }

    // staging: row = tid>>2 (0..127), logical slot = ((tid&3) - row>>1)&3
    // (row+128 preserves slot since 64 ≡ 0 mod 4).
    int row0 = tid >> 2;
    int ls   = ((tid & 3) - (row0 >> 1)) & 3;
    long a0 = (long)(bm + row0) * lda + ls * 8;
    long a1 = a0 + 128L * lda;
    long b0 = (long)(bn + row0) * ldb + ls * 8;
    int dA0 = tid * 8, dA1 = tid * 8 + 4096, dB = tid * 8;

    f32x4 acc[4][4] = {};
    int nt = K >> 6;

    // prologue: tile 0 (Ak0,Bk0,Ak1,Bk1), publish Ak0/Bk0
    gload16(A + a0, &ldsA[0][0][dA0]); gload16(A + a1, &ldsA[0][0][dA1]);
    gload16(B + b0, &ldsB[0][0][dB]);
    gload16(A + a0 + 32, &ldsA[0][1][dA0]); gload16(A + a1 + 32, &ldsA[0][1][dA1]);
    gload16(B + b0 + 32, &ldsB[0][1][dB]);
    asm volatile("s_waitcnt vmcnt(3)" ::: "memory");
    __builtin_amdgcn_s_barrier();

    for (int t = 0; t < nt; ++t) {
        int cur = t & 1, nxt = cur ^ 1;
        long kn = (long)(t + 1) * 64;
        bool pf = (t + 1 < nt);
        bf16x8 af[4], bf[4];

        // ---- P1: ks=0, ni 0..1 ----
        #pragma unroll
        for (int mi = 0; mi < 4; ++mi) af[mi] = *(const bf16x8*)&ldsA[cur][0][offA[mi]];
        bf[0] = *(const bf16x8*)&ldsB[cur][0][offB[0]];
        bf[1] = *(const bf16x8*)&ldsB[cur][0][offB[1]];
        if (pf) { gload16(A + a0 + kn, &ldsA[nxt][0][dA0]);
                  gload16(A + a1 + kn, &ldsA[nxt][0][dA1]); }
        __builtin_amdgcn_s_barrier();
        __builtin_amdgcn_s_setprio(1);
        #pragma unroll
        for (int mi = 0; mi < 4; ++mi)
            #pragma unroll
            for (int ni = 0; ni < 2; ++ni)
                acc[mi][ni] = __builtin_amdgcn_mfma_f32_16x16x32_bf16(
                    af[mi], bf[ni], acc[mi][ni], 0, 0, 0);
        __builtin_amdgcn_s_setprio(0);
        __builtin_amdgcn_s_barrier();

        // ---- P2: ks=0, ni 2..3 (af kept in regs) ----
        bf[2] = *(const bf16x8*)&ldsB[cur][0][offB[2]];
        bf[3] = *(const bf16x8*)&ldsB[cur][0][offB[3]];
        if (pf) gload16(B + b0 + kn, &ldsB[nxt][0][dB]);
        // publish Ak1/Bk1(t)
        if (pf) asm volatile("s_waitcnt vmcnt(3)" ::: "memory");
        else    asm volatile("s_waitcnt vmcnt(0)" ::: "memory");
        __builtin_amdgcn_s_barrier();
        __builtin_amdgcn_s_setprio(1);
        #pragma unroll
        for (int mi = 0; mi < 4; ++mi)
            #pragma unroll
            for (int ni = 2; ni < 4; ++ni)
                acc[mi][ni] = __builtin_amdgcn_mfma_f32_16x16x32_bf16(
                    af[mi], bf[ni], acc[mi][ni], 0, 0, 0);
        __builtin_amdgcn_s_setprio(0);
        __builtin_amdgcn_s_barrier();

        // ---- P3: ks=1, ni 0..1 ----
        #pragma unroll
        for (int mi = 0; mi < 4; ++mi) af[mi] = *(const bf16x8*)&ldsA[cur][1][offA[mi]];
        bf[0] = *(const bf16x8*)&ldsB[cur][1][offB[0]];
        bf[1] = *(const bf16x8*)&ldsB[cur][1][offB[1]];
        if (pf) { gload16(A + a0 + kn + 32, &ldsA[nxt][1][dA0]);
                  gload16(A + a1 + kn + 32, &ldsA[nxt][1][dA1]); }
        __builtin_amdgcn_s_barrier();
        __builtin_amdgcn_s_setprio(1);
        #pragma unroll
        for (int mi = 0; mi < 4; ++mi)
            #pragma unroll
            for (int ni = 0; ni < 2; ++ni)
                acc[mi][ni] = __builtin_amdgcn_mfma_f32_16x16x32_bf16(
                    af[mi], bf[ni], acc[mi][ni], 0, 0, 0);
        __builtin_amdgcn_s_setprio(0);
        __builtin_amdgcn_s_barrier();

        // ---- P4: ks=1, ni 2..3 ----
        bf[2] = *(const bf16x8*)&ldsB[cur][1][offB[2]];
        bf[3] = *(const bf16x8*)&ldsB[cur][1][offB[3]];
        if (pf) gload16(B + b0 + kn + 32, &ldsB[nxt][1][dB]);
        // publish Ak0/Bk0(t+1)
        if (pf) asm volatile("s_waitcnt vmcnt(3)" ::: "memory");
        __builtin_amdgcn_s_barrier();
        __builtin_amdgcn_s_setprio(1);
        #pragma unroll
        for (int mi = 0; mi < 4; ++mi)
            #pragma unroll
            for (int ni = 2; ni < 4; ++ni)
                acc[mi][ni] = __builtin_amdgcn_mfma_f32_16x16x32_bf16(
                    af[mi], bf[ni], acc[mi][ni], 0, 0, 0);
        __builtin_amdgcn_s_setprio(0);
        __builtin_amdgcn_s_barrier();
    }

    // epilogue: C/D layout col=lane&15, row=quad*4+reg
    if (STORE_TRANS) {
        unsigned short* vt = (unsigned short*)Cp;
        #pragma unroll
        for (int mi = 0; mi < 4; ++mi) {
            #pragma unroll
            for (int ni = 0; ni < 4; ++ni) {
                int row = bm + wm + mi * 16 + quad * 4;   // 4 consecutive rows
                int col = bn + wn + ni * 16 + l15;
                ushort4v o;
                #pragma unroll
                for (int r = 0; r < 4; ++r) o[r] = f2bf(acc[mi][ni][r] * alpha);
                *(ushort4v*)(vt + (long)(row >> 10) * 2097152
                                + (long)col * 1024 + (row & 1023)) = o;
            }
        }
    } else {
        #pragma unroll
        for (int mi = 0; mi < 4; ++mi)
            #pragma unroll
            for (int ni = 0; ni < 4; ++ni)
                #pragma unroll
                for (int r = 0; r < 4; ++r) {
                    int row = bm + wm + mi * 16 + quad * 4 + r;
                    int col = bn + wn + ni * 16 + l15;
                    ((unsigned short*)Cp)[(long)row * ldc + col] =
                        f2bf(acc[mi][ni][r] * alpha);
                }
    }
}

// ---------------------------------------------------------------------------
// gemm256: 256x256 tile, BK=64, 8 waves (2M x 4N), 4 phases per K-tile.
// (verified round 3; used for out-proj). Publish: prologue vmcnt(4);
// end-P2 vmcnt(4) [last: vmcnt(0)]; end-P4 vmcnt(4) [skip last].
// ---------------------------------------------------------------------------
template<int RESID, int STORE_TRANS>
__global__ __launch_bounds__(512, 2) void gemm256_kernel(
    const unsigned short* __restrict__ A, const unsigned short* __restrict__ B,
    void* __restrict__ Cp, const unsigned short* __restrict__ resid,
    int K, int lda, int ldb, int ldc, float alpha)
{
    // [buf][half-tile: 0=Ak0 1=Ak1 2=Bk0 3=Bk1][8192 ushorts = 16KB]
    __shared__ unsigned short lds[2][4][8192];

    // bijective XCD swizzle (m204)
    int nwg = gridDim.x * gridDim.y;
    int flat = blockIdx.y * gridDim.x + blockIdx.x;
    int qq = nwg >> 3, rr = nwg & 7;
    int xcd = flat & 7, idx = flat >> 3;
    int sid = (xcd < rr ? xcd * (qq + 1) : rr * (qq + 1) + (xcd - rr) * qq) + idx;
    int bx = sid % gridDim.x, by = sid / gridDim.x;
    int bm = by * 256, bn = bx * 256;

    int tid = threadIdx.x;
    int lane = tid & 63, wave = tid >> 6;
    int l15 = lane & 15, quad = lane >> 4;
    int wm = (wave >> 2) * 128;     // 0 or 128
    int wn = (wave & 3) * 64;       // 0,64,128,192

    int offA[8], offB[4];
    #pragma unroll
    for (int mi = 0; mi < 8; ++mi) {
        int r = wm + mi * 16 + l15;
        offA[mi] = r * 32 + (((quad + (r >> 1)) & 3) << 3);
    }
    #pragma unroll
    for (int ni = 0; ni < 4; ++ni) {
        int c = wn + ni * 16 + l15;
        offB[ni] = c * 32 + (((quad + (c >> 1)) & 3) << 3);
    }

    int row0 = tid >> 2;
    int ls   = ((tid & 3) - (row0 >> 1)) & 3;
    long a0 = (long)(bm + row0) * lda + ls * 8;
    long a1 = a0 + 128L * lda;
    long b0 = (long)(bn + row0) * ldb + ls * 8;
    long b1 = b0 + 128L * ldb;
    int d0 = tid * 8, d1 = tid * 8 + 4096;

    f32x4 acc[8][4] = {};
    int nt = K >> 6;

    gload16(A + a0, &lds[0][0][d0]); gload16(A + a1, &lds[0][0][d1]);           // Ak0
    gload16(B + b0, &lds[0][2][d0]); gload16(B + b1, &lds[0][2][d1]);           // Bk0
    gload16(A + a0 + 32, &lds[0][1][d0]); gload16(A + a1 + 32, &lds[0][1][d1]); // Ak1
    gload16(B + b0 + 32, &lds[0][3][d0]); gload16(B + b1 + 32, &lds[0][3][d1]); // Bk1
    asm volatile("s_waitcnt vmcnt(4)" ::: "memory");
    __builtin_amdgcn_s_barrier();

    for (int t = 0; t < nt; ++t) {
        int cur = t & 1, nxt = cur ^ 1;
        long kn = (long)(t + 1) * 64;
        bool pf = (t + 1 < nt);
        bf16x8 af[4], bf[4];

        // ---- P1: ks=0, mi 0..3 ----
        #pragma unroll
        for (int mi = 0; mi < 4; ++mi) af[mi] = *(const bf16x8*)&lds[cur][0][offA[mi]];
        #pragma unroll
        for (int ni = 0; ni < 4; ++ni) bf[ni] = *(const bf16x8*)&lds[cur][2][offB[ni]];
        if (pf) { gload16(A + a0 + kn, &lds[nxt][0][d0]);
                  gload16(A + a1 + kn, &lds[nxt][0][d1]); }
        __builtin_amdgcn_s_barrier();
        __builtin_amdgcn_s_setprio(1);
        #pragma unroll
        for (int mi = 0; mi < 4; ++mi)
            #pragma unroll
            for (int ni = 0; ni < 4; ++ni)
                acc[mi][ni] = __builtin_amdgcn_mfma_f32_16x16x32_bf16(
                    af[mi], bf[ni], acc[mi][ni], 0, 0, 0);
        __builtin_amdgcn_s_setprio(0);
        __builtin_amdgcn_s_barrier();

        // ---- P2: ks=0, mi 4..7 ----
        #pragma unroll
        for (int mi = 0; mi < 4; ++mi) af[mi] = *(const bf16x8*)&lds[cur][0][offA[mi + 4]];
        if (pf) { gload16(B + b0 + kn, &lds[nxt][2][d0]);
                  gload16(B + b1 + kn, &lds[nxt][2][d1]); }
        if (pf) asm volatile("s_waitcnt vmcnt(4)" ::: "memory");
        else    asm volatile("s_waitcnt vmcnt(0)" ::: "memory");
        __builtin_amdgcn_s_barrier();
        __builtin_amdgcn_s_setprio(1);
        #pragma unroll
        for (int mi = 0; mi < 4; ++mi)
            #pragma unroll
            for (int ni = 0; ni < 4; ++ni)
                acc[mi + 4][ni] = __builtin_amdgcn_mfma_f32_16x16x32_bf16(
                    af[mi], bf[ni], acc[mi + 4][ni], 0, 0, 0);
        __builtin_amdgcn_s_setprio(0);
        __builtin_amdgcn_s_barrier();

        // ---- P3: ks=1, mi 0..3 ----
        #pragma unroll
        for (int mi = 0; mi < 4; ++mi) af[mi] = *(const bf16x8*)&lds[cur][1][offA[mi]];
        #pragma unroll
        for (int ni = 0; ni < 4; ++ni) bf[ni] = *(const bf16x8*)&lds[cur][3][offB[ni]];
        if (pf) { gload16(A + a0 + kn + 32, &lds[nxt][1][d0]);
                  gload16(A + a1 + kn + 32, &lds[nxt][1][d1]); }
        __builtin_amdgcn_s_barrier();
        __builtin_amdgcn_s_setprio(1);
        #pragma unroll
        for (int mi = 0; mi < 4; ++mi)
            #pragma unroll
            for (int ni = 0; ni < 4; ++ni)
                acc[mi][ni] = __builtin_amdgcn_mfma_f32_16x16x32_bf16(
                    af[mi], bf[ni], acc[mi][ni], 0, 0, 0);
        __builtin_amdgcn_s_setprio(0);
        __builtin_amdgcn_s_barrier();

        // ---- P4: ks=1, mi 4..7 ----
        #pragma unroll
        for (int mi = 0; mi < 4; ++mi) af[mi] = *(const bf16x8*)&lds[cur][1][offA[mi + 4]];
        if (pf) { gload16(B + b0 + kn + 32, &lds[nxt][3][d0]);
                  gload16(B + b1 + kn + 32, &lds[nxt][3][d1]); }
        if (pf) asm volatile("s_waitcnt vmcnt(4)" ::: "memory");
        __builtin_amdgcn_s_barrier();
        __builtin_amdgcn_s_setprio(1);
        #pragma unroll
        for (int mi = 0; mi < 4; ++mi)
            #pragma unroll
            for (int ni = 0; ni < 4; ++ni)
                acc[mi + 4][ni] = __builtin_amdgcn_mfma_f32_16x16x32_bf16(
                    af[mi], bf[ni], acc[mi + 4][ni], 0, 0, 0);
        __builtin_amdgcn_s_setprio(0);
        __builtin_amdgcn_s_barrier();
    }

    if (STORE_TRANS) {
        unsigned short* vt = (unsigned short*)Cp;
        #pragma unroll
        for (int mi = 0; mi < 8; ++mi) {
            #pragma unroll
            for (int ni = 0; ni < 4; ++ni) {
                int row = bm + wm + mi * 16 + quad * 4;
                int col = bn + wn + ni * 16 + l15;
                ushort4v o;
                #pragma unroll
                for (int r = 0; r < 4; ++r) o[r] = f2bf(acc[mi][ni][r] * alpha);
                *(ushort4v*)(vt + (long)(row >> 10) * 2097152
                                + (long)col * 1024 + (row & 1023)) = o;
            }
        }
    } else {
        #pragma unroll
        for (int mi = 0; mi < 8; ++mi)
            #pragma unroll
            for (int ni = 0; ni < 4; ++ni)
                #pragma unroll
                for (int r = 0; r < 4; ++r) {
                    int row = bm + wm + mi * 16 + quad * 4 + r;
                    int col = bn + wn + ni * 16 + l15;
                    float v = acc[mi][ni][r] * alpha;
                    long ci = (long)row * ldc + col;
                    if (RESID) v += bf2f(resid[ci]);
                    ((unsigned short*)Cp)[ci] = f2bf(v);
                }
    }
}

// ---------------------------------------------------------------------------
// MFMA GEMM, m97 structure (used for attention QK^T and PV only).
// ---------------------------------------------------------------------------
template<int OUT_F32, int RESID, int STORE_TRANS>
__global__ __launch_bounds__(256) void gemm_kernel(
    const unsigned short* __restrict__ A, const unsigned short* __restrict__ B,
    void* __restrict__ Cp, const unsigned short* __restrict__ resid,
    int K, int lda, int ldb, int ldc,
    long sA2, long sB2, long sC2, float alpha)
{
    __shared__ unsigned short As[128 * 32];
    __shared__ unsigned short Bs[128 * 32];

    int z = blockIdx.z;
    const unsigned short* Ab = A + (long)z * sA2;
    const unsigned short* Bb = B + (long)z * sB2;
    long coff = (long)z * sC2;

    int bm = blockIdx.y * 128, bn = blockIdx.x * 128;
    int tid = threadIdx.x;
    int lane = tid & 63;
    int wave = tid >> 6;
    int wm = (wave >> 1) * 64, wn = (wave & 1) * 64;
    int l15 = lane & 15, quad = lane >> 4;

    int c1 = tid + 256;
    int r0 = tid >> 2, g0 = (tid & 3) * 8;
    int r1 = c1 >> 2,  g1 = (c1 & 3) * 8;

    const unsigned short* a0p = Ab + (long)(bm + r0) * lda + g0;
    const unsigned short* a1p = Ab + (long)(bm + r1) * lda + g1;
    const unsigned short* b0p = Bb + (long)(bn + r0) * ldb + g0;
    const unsigned short* b1p = Bb + (long)(bn + r1) * ldb + g1;
    unsigned short* al0 = As + tid * 8;
    unsigned short* al1 = As + c1 * 8;
    unsigned short* bl0 = Bs + tid * 8;
    unsigned short* bl1 = Bs + c1 * 8;

    f32x4 acc[4][4] = {};

    for (int k0 = 0; k0 < K; k0 += 32) {
        gload16(a0p + k0, al0);
        gload16(a1p + k0, al1);
        gload16(b0p + k0, bl0);
        gload16(b1p + k0, bl1);
        __syncthreads();

        bf16x8 af[4], bfv[4];
        #pragma unroll
        for (int mi = 0; mi < 4; ++mi)
            af[mi] = *(const bf16x8*)&As[(wm + mi * 16 + l15) * 32 + quad * 8];
        #pragma unroll
        for (int ni = 0; ni < 4; ++ni)
            bfv[ni] = *(const bf16x8*)&Bs[(wn + ni * 16 + l15) * 32 + quad * 8];
        #pragma unroll
        for (int mi = 0; mi < 4; ++mi)
            #pragma unroll
            for (int ni = 0; ni < 4; ++ni)
                acc[mi][ni] = __builtin_amdgcn_mfma_f32_16x16x32_bf16(
                    af[mi], bfv[ni], acc[mi][ni], 0, 0, 0);
        __syncthreads();
    }

    if (STORE_TRANS) {
        unsigned short* vt = (unsigned short*)Cp;
        #pragma unroll
        for (int mi = 0; mi < 4; ++mi) {
            #pragma unroll
            for (int ni = 0; ni < 4; ++ni) {
                int row = bm + wm + mi * 16 + quad * 4;
                int col = bn + wn + ni * 16 + l15;
                ushort4v o;
                #pragma unroll
                for (int r = 0; r < 4; ++r) o[r] = f2bf(acc[mi][ni][r] * alpha);
                *(ushort4v*)(vt + (long)(row >> 10) * 2097152
                                + (long)col * 1024 + (row & 1023)) = o;
            }
        }
    } else {
        #pragma unroll
        for (int mi = 0; mi < 4; ++mi)
            #pragma unroll
            for (int ni = 0; ni < 4; ++ni)
                #pragma unroll
                for (int r = 0; r < 4; ++r) {
                    int row = bm + wm + mi * 16 + quad * 4 + r;
                    int col = bn + wn + ni * 16 + l15;
                    float v = acc[mi][ni][r] * alpha;
                    long ci = coff + (long)row * ldc + col;
                    if (RESID) v += bf2f(resid[ci]);
                    if (OUT_F32) ((float*)Cp)[ci] = v;
                    else         ((unsigned short*)Cp)[ci] = f2bf(v);
                }
    }
}

// ---------------------------------------------------------------------------
// Row softmax over f32 scores; writes bf16 P IN-PLACE (row r bf16 at ushort
// offset r*2048). Safe: loads precede the block barriers that precede writes.
// ---------------------------------------------------------------------------
__global__ __launch_bounds__(256) void softmax_kernel(float* __restrict__ s)
{
    long row = blockIdx.x;                   // 8192 rows = 8 heads x 1024
    float* p = s + row * 1024;
    unsigned short* dst = (unsigned short*)s + row * 2048;
    int tid = threadIdx.x;
    int lane = tid & 63, wv = tid >> 6;

    f32x4 v = *(const f32x4*)(p + tid * 4);
    float m = fmaxf(fmaxf(v[0], v[1]), fmaxf(v[2], v[3]));
    #pragma unroll
    for (int off = 32; off; off >>= 1) m = fmaxf(m, __shfl_xor(m, off, 64));
    __shared__ float redm[4];
    if (lane == 0) redm[wv] = m;
    __syncthreads();
    m = fmaxf(fmaxf(redm[0], redm[1]), fmaxf(redm[2], redm[3]));

    f32x4 e;
    e[0] = __expf(v[0] - m); e[1] = __expf(v[1] - m);
    e[2] = __expf(v[2] - m); e[3] = __expf(v[3] - m);
    float sum = e[0] + e[1] + e[2] + e[3];
    #pragma unroll
    for (int off = 32; off; off >>= 1) sum += __shfl_xor(sum, off, 64);
    __shared__ float reds[4];
    if (lane == 0) reds[wv] = sum;
    __syncthreads();
    sum = reds[0] + reds[1] + reds[2] + reds[3];

    float inv = 1.0f / sum;
    ushort4v o;
    o[0] = f2bf(e[0] * inv); o[1] = f2bf(e[1] * inv);
    o[2] = f2bf(e[2] * inv); o[3] = f2bf(e[3] * inv);
    *(ushort4v*)(dst + tid * 4) = o;
}

// ---------------------------------------------------------------------------
// LayerNorm pass 1: per-batch sum/sumsq over bf16 zo [1024*8192].
// ---------------------------------------------------------------------------
__global__ __launch_bounds__(256) void ln_stats_kernel(
    const unsigned short* __restrict__ zo, float* __restrict__ stats)
{
    int b = blockIdx.y;
    const ushort8* p = (const ushort8*)(zo + (long)b * 8388608);
    float s = 0.f, sq = 0.f;
    for (int i = blockIdx.x * 256 + threadIdx.x; i < 1048576; i += 128 * 256) {
        ushort8 u = p[i];
        #pragma unroll
        for (int e = 0; e < 8; ++e) {
            float f = bf2f(u[e]);
            s += f; sq += f * f;
        }
    }
    #pragma unroll
    for (int off = 32; off; off >>= 1) {
        s += __shfl_xor(s, off, 64);
        sq += __shfl_xor(sq, off, 64);
    }
    __shared__ float rs[4], rq[4];
    int lane = threadIdx.x & 63, wv = threadIdx.x >> 6;
    if (lane == 0) { rs[wv] = s; rq[wv] = sq; }
    __syncthreads();
    if (threadIdx.x == 0) {
        atomicAdd(&stats[b * 2 + 0], rs[0] + rs[1] + rs[2] + rs[3]);
        atomicAdd(&stats[b * 2 + 1], rq[0] + rq[1] + rq[2] + rq[3]);
    }
}

// ---------------------------------------------------------------------------
// LayerNorm apply + gamma/beta (f32) + 'b (h w) (n c) -> b n c h w' permute.
// ---------------------------------------------------------------------------
__global__ __launch_bounds__(256) void ln_apply_kernel(
    const unsigned short* __restrict__ zo,
    const float* __restrict__ gamma,
    const float* __restrict__ beta,
    const float* __restrict__ stats,
    float* __restrict__ out)
{
    __shared__ float tile[64][65];
    int b = blockIdx.z, t0 = blockIdx.y * 64, f0 = blockIdx.x * 64;
    float mean = stats[b * 2 + 0] * (1.0f / 8388608.0f);
    float var  = stats[b * 2 + 1] * (1.0f / 8388608.0f) - mean * mean;
    float rstd = rsqrtf(var + 1e-6f);
    int tid = threadIdx.x;

    #pragma unroll
    for (int i = 0; i < 4; ++i) {
        int rt = (tid >> 4) + i * 16;   // token-local 0..63
        int c4 = (tid & 15) * 4;        // f-local
        long zi = (long)b * 8388608 + (long)(t0 + rt) * 8192 + f0 + c4;
        ushort4v zv = *(const ushort4v*)(zo + zi);
        long gi = (long)(t0 + rt) * 8192 + f0 + c4;
        f32x4 g  = *(const f32x4*)(gamma + gi);
        f32x4 bt = *(const f32x4*)(beta + gi);
        #pragma unroll
        for (int e = 0; e < 4; ++e)
            tile[rt][c4 + e] = (bf2f(zv[e]) - mean) * rstd * g[e] + bt[e];
    }
    __syncthreads();

    int fl = tid >> 2;                  // f-local 0..63
    int tg = tid & 3;                   // token group (16 tokens each)
    int f = f0 + fl;
    int np = f >> 10, cp = f & 1023;
    long obase = ((long)((b * 8 + np) * 1024 + cp)) * 1024 + t0 + tg * 16;
    #pragma unroll
    for (int c = 0; c < 4; ++c) {
        f32x4 o;
        #pragma unroll
        for (int e = 0; e < 4; ++e) o[e] = tile[tg * 16 + c * 4 + e][fl];
        *(f32x4*)(out + obase + c * 4) = o;
    }
}

// ---------------------------------------------------------------------------
extern "C" void kernel_launch(void* const* d_in, const int* in_sizes, int n_in,
                              void* d_out, int out_size, void* d_ws, size_t ws_size,
                              hipStream_t stream)
{
    const float* ref_img = (const float*)d_in[0];
    const float* hdmap   = (const float*)d_in[1];
    const float* w_q     = (const float*)d_in[2];
    const float* w_k     = (const float*)d_in[3];
    const float* w_v     = (const float*)d_in[4];
    const float* w_o     = (const float*)d_in[5];
    const float* gamma   = (const float*)d_in[6];
    const float* beta    = (const float*)d_in[7];

    char* ws = (char*)d_ws;
    const size_t MB = 1024 * 1024;
    unsigned short* x  = (unsigned short*)(ws);              // [0,64M) -> zo in-place
    unsigned short* q  = (unsigned short*)(ws + 64 * MB);    // [64,80M) -> z2
    unsigned short* k  = (unsigned short*)(ws + 80 * MB);    // [80,96M)
    unsigned short* vT = (unsigned short*)(ws + 96 * MB);    // [96,112M)
    unsigned short* wT = (unsigned short*)(ws + 112 * MB);   // [112,144M) scratch
    float* sc          = (float*)(ws + 112 * MB);            // same window as wT
    float* stats       = (float*)(ws + 144 * MB);            // 32 B
    unsigned short* z2 = q;
    unsigned short* zo = x;

    hipMemsetAsync(stats, 0, 32, stream);

    build_x_kernel<<<dim3(16, 1024), 256, 0, stream>>>(ref_img, hdmap, x);

    // --- QKV projections: wconv to bf16 [2048][8192], then 256x128 GEMM
    //     (grid 16x16 = 256 wgs = full chip; round-3 fix) ---
    wconv_kernel<<<dim3(128, 32), 256, 0, stream>>>(w_q, wT, 8192, 2048);
    gemm256x128_kernel<0><<<dim3(16, 16), 512, 0, stream>>>(
        x, wT, q, 8192, 8192, 8192, 2048, 1.0f);

    wconv_kernel<<<dim3(128, 32), 256, 0, stream>>>(w_k, wT, 8192, 2048);
    gemm256x128_kernel<0><<<dim3(16, 16), 512, 0, stream>>>(
        x, wT, k, 8192, 8192, 8192, 2048, 1.0f);

    wconv_kernel<<<dim3(128, 32), 256, 0, stream>>>(w_v, wT, 8192, 2048);
    gemm256x128_kernel<1><<<dim3(16, 16), 512, 0, stream>>>(   // V stored transposed
        x, wT, vT, 8192, 8192, 8192, 0, 1.0f);

    // --- attention, batch-sequential (sc window = 32 MiB, all 8 heads) ---
    for (int b = 0; b < 4; ++b) {
        long o2 = (long)b * 2097152;
        // sc[h] = (1/16) Q_bh @ K_bh^T
        gemm_kernel<1,0,0><<<dim3(8, 8, 8), 256, 0, stream>>>(
            q + o2, k + o2, sc, nullptr,
            256, 2048, 2048, 1024, 256L, 256L, 1048576L, 0.0625f);
        softmax_kernel<<<8192, 256, 0, stream>>>(sc);        // writes bf16 P in-place
        // z2[b,h] = P_h @ V_bh
        gemm_kernel<0,0,0><<<dim3(2, 8, 8), 256, 0, stream>>>(
            (const unsigned short*)sc, vT + o2, z2 + o2, nullptr,
            1024, 2048, 1024, 2048, 2097152L, 262144L, 256L, 1.0f);
    }

    // --- out projection: wT_o bf16 [8192][2048]; zo written in-place over x ---
    wconv_kernel<<<dim3(32, 128), 256, 0, stream>>>(w_o, wT, 2048, 8192);
    gemm256_kernel<1,0><<<dim3(32, 16), 512, 0, stream>>>(
        z2, wT, zo, x, 2048, 2048, 2048, 8192, 1.0f);

    ln_stats_kernel<<<dim3(128, 4), 256, 0, stream>>>(zo, stats);
    ln_apply_kernel<<<dim3(128, 16, 4), 256, 0, stream>>>(
        zo, gamma, beta, stats, (float*)d_out);
}